// Round 1
// baseline (395.360 us; speedup 1.0000x reference)
//
#include <hip/hip_runtime.h>
#include <hip/hip_bf16.h>

#define BATCH 8
#define CH    256
#define NTOK  4096

typedef __bf16 bf16_t;
typedef __bf16 bf16x8 __attribute__((ext_vector_type(8)));
typedef __bf16 bf16x4 __attribute__((ext_vector_type(4)));
typedef float  fx4    __attribute__((ext_vector_type(4)));

// MFMA lane layouts (gfx950, m89/m120-verified):
//   A[m=lane&15][k=quad*8+j], B[k=quad*8+j][n=lane&15], D[row=quad*4+reg][col=lane&15]

// ---------------------------------------------------------------------------
// Projection: out[n][d] = sum_c W[d][c] * X[b][c][n] + bias[d]   (3 mats)
//   Q -> qg[b][n][d] * 1/16 (scale folded, exact pow2)
//   K -> kg[b][n][d]
//   V -> vg[b][d][n]
// LDS: Xt bf16[64][264] @0 (33792) | Wl bf16[256][40] @33792 (20480)
//      OutL bf16[256][72] @0 (reuse) | biasL f32[256] @55296
__global__ __launch_bounds__(256, 2) void proj_kernel(
    const float* __restrict__ x, const float* __restrict__ motion,
    const float* __restrict__ wq, const float* __restrict__ bq,
    const float* __restrict__ wk, const float* __restrict__ bk,
    const float* __restrict__ wv, const float* __restrict__ bv,
    bf16_t* __restrict__ qg, bf16_t* __restrict__ kg, bf16_t* __restrict__ vg)
{
    const int mat = blockIdx.y;
    const int b   = blockIdx.x & 7;
    const int n0  = (blockIdx.x >> 3) * 64;
    const float* __restrict__ src  = (mat == 0) ? x  : motion;
    const float* __restrict__ W    = (mat == 0) ? wq : (mat == 1 ? wk : wv);
    const float* __restrict__ bias = (mat == 0) ? bq : (mat == 1 ? bk : bv);

    __shared__ __align__(16) unsigned char smem[55296 + 1024];
    bf16_t* Xt    = (bf16_t*)smem;              // [64][264]  n-major, c contig
    bf16_t* Wl    = (bf16_t*)(smem + 33792);    // [256][40]  d-major, 32c chunk
    bf16_t* OutL  = (bf16_t*)smem;              // [256][72]  reused after GEMM
    float*  biasL = (float*)(smem + 55296);     // [256]

    const int tid  = threadIdx.x;
    const int w    = tid >> 6;
    const int lane = tid & 63;
    const int l16  = lane & 15;
    const int quad = lane >> 4;

    biasL[tid] = bias[tid];

    // stage Xt[j][c] = src[b][c][n0+j] (fp32->bf16, transpose in LDS)
    for (int it = 0; it < 16; ++it) {
        const int c  = it * 16 + (tid >> 4);
        const int j4 = (tid & 15) * 4;
        const float4 v = *(const float4*)&src[((size_t)b * CH + c) * NTOK + n0 + j4];
        Xt[(j4 + 0) * 264 + c] = (bf16_t)v.x;
        Xt[(j4 + 1) * 264 + c] = (bf16_t)v.y;
        Xt[(j4 + 2) * 264 + c] = (bf16_t)v.z;
        Xt[(j4 + 3) * 264 + c] = (bf16_t)v.w;
    }

    fx4 acc[16];
    for (int i = 0; i < 16; ++i) acc[i] = (fx4){0.f, 0.f, 0.f, 0.f};

    for (int cs = 0; cs < 8; ++cs) {
        // stage Wl[d][cc] = W[d][cs*32+cc], bf16
        for (int it = 0; it < 8; ++it) {
            const int d  = it * 32 + (tid >> 3);
            const int c4 = (tid & 7) * 4;
            const float4 v = *(const float4*)&W[(size_t)d * CH + cs * 32 + c4];
            bf16x4 pk;
            pk[0] = (bf16_t)v.x; pk[1] = (bf16_t)v.y;
            pk[2] = (bf16_t)v.z; pk[3] = (bf16_t)v.w;
            *(bf16x4*)&Wl[d * 40 + c4] = pk;
        }
        __syncthreads();
        // wave w owns n-rows [w*16, w*16+16); A-frag same for all 16 d-patches
        const bf16x8 af = *(const bf16x8*)&Xt[(w * 16 + l16) * 264 + cs * 32 + quad * 8];
        for (int dp = 0; dp < 16; ++dp) {
            const bf16x8 bf = *(const bf16x8*)&Wl[(dp * 16 + l16) * 40 + quad * 8];
            acc[dp] = __builtin_amdgcn_mfma_f32_16x16x32_bf16(af, bf, acc[dp], 0, 0, 0);
        }
        __syncthreads();
    }

    // epilogue: +bias, Q pre-scaled by 1/16 (exact), park in OutL[d][n]
    const float qs = (mat == 0) ? 0.0625f : 1.0f;
    for (int dp = 0; dp < 16; ++dp) {
        const int d = dp * 16 + l16;
        const float bb = biasL[d];
        bf16x4 pk;
        for (int r = 0; r < 4; ++r)
            pk[r] = (bf16_t)((acc[dp][r] + bb) * qs);
        *(bf16x4*)&OutL[d * 72 + w * 16 + quad * 4] = pk;   // D: row n=quad*4+r, col d=l16
    }
    __syncthreads();

    if (mat < 2) {  // Q/K -> [b][n][d], coalesced 16B stores
        bf16_t* __restrict__ G = (mat == 0) ? qg : kg;
        for (int it = 0; it < 8; ++it) {
            const int n  = it * 8 + (tid >> 5);
            const int d8 = (tid & 31) * 8;
            bf16x8 vv;
            for (int k = 0; k < 8; ++k) vv[k] = OutL[(d8 + k) * 72 + n];
            *(bf16x8*)&G[((size_t)b * NTOK + n0 + n) * CH + d8] = vv;
        }
    } else {        // V -> [b][d][n]
        for (int it = 0; it < 8; ++it) {
            const int d  = it * 32 + (tid >> 3);
            const int n8 = (tid & 7) * 8;
            const bf16x8 vv = *(const bf16x8*)&OutL[d * 72 + n8];
            *(bf16x8*)&vg[((size_t)b * CH + d) * NTOK + n0 + n8] = vv;
        }
    }
}

// ---------------------------------------------------------------------------
// Attention, flash-style without max-subtraction (logits provably ~ +-1):
// per block: batch b (blockIdx&7 -> XCD locality), i-tile of 64.
// wave w owns i-strip [w*16, w*16+16); Q frags live in registers (scale folded).
// Loop j-tiles of 32: S=Q^T K (MFMA), p=exp(s) fp32, rowsum in regs,
// P -> LDS (C/D layout -> B-operand layout), O += V P^T (MFMA). Divide at end.
// LDS: Kt bf16[32][264] @0 | Vt bf16[256][40] @16896 | Pb bf16[4][16][40] @37376
//      lred f32[64] @42496  -> total 42752 B => 3 blocks/CU
__global__ __launch_bounds__(256, 3) void attn_kernel(
    const bf16_t* __restrict__ qg, const bf16_t* __restrict__ kg,
    const bf16_t* __restrict__ vg, float* __restrict__ out)
{
    const int b  = blockIdx.x & 7;
    const int i0 = (blockIdx.x >> 3) * 64;

    __shared__ __align__(16) unsigned char smem[42752];
    bf16_t* Kt   = (bf16_t*)smem;             // [32][264] j-major, c contig
    bf16_t* Vt   = (bf16_t*)(smem + 16896);   // [256][40] c-major, j contig
    bf16_t* Pb   = (bf16_t*)(smem + 37376);   // [4][16][40] per-wave P tile
    float*  lred = (float*)(smem + 42496);    // [64] row sums

    const int tid = threadIdx.x;
    const int w = tid >> 6, lane = tid & 63, l16 = lane & 15, quad = lane >> 4;

    // Q A-frags: i = i0 + w*16 + l16, c = cs*32 + quad*8 + [0..7]
    bf16x8 qf[8];
    {
        const bf16_t* qb = qg + ((size_t)b * NTOK + i0 + w * 16 + l16) * CH;
        for (int cs = 0; cs < 8; ++cs)
            qf[cs] = *(const bf16x8*)&qb[cs * 32 + quad * 8];
    }

    fx4 oacc[16];
    for (int i = 0; i < 16; ++i) oacc[i] = (fx4){0.f, 0.f, 0.f, 0.f};
    float rs[4] = {0.f, 0.f, 0.f, 0.f};

    bf16_t* PbW = Pb + w * (16 * 40);

    for (int jt = 0; jt < 128; ++jt) {
        const int j0 = jt * 32;
        for (int it = 0; it < 4; ++it) {       // Kt[j][c]
            const int j  = it * 8 + (tid >> 5);
            const int c8 = (tid & 31) * 8;
            *(bf16x8*)&Kt[j * 264 + c8] =
                *(const bf16x8*)&kg[((size_t)b * NTOK + j0 + j) * CH + c8];
        }
        for (int it = 0; it < 4; ++it) {       // Vt[c][j]
            const int c  = it * 64 + (tid >> 2);
            const int j8 = (tid & 3) * 8;
            *(bf16x8*)&Vt[c * 40 + j8] =
                *(const bf16x8*)&vg[((size_t)b * CH + c) * NTOK + j0 + j8];
        }
        __syncthreads();

        // S strip: i = i0+w*16+(quad*4+r), j = j0+jp*16+l16
        for (int jp = 0; jp < 2; ++jp) {
            fx4 s = (fx4){0.f, 0.f, 0.f, 0.f};
            for (int cs = 0; cs < 8; ++cs) {
                const bf16x8 kf =
                    *(const bf16x8*)&Kt[(jp * 16 + l16) * 264 + cs * 32 + quad * 8];
                s = __builtin_amdgcn_mfma_f32_16x16x32_bf16(qf[cs], kf, s, 0, 0, 0);
            }
            for (int r = 0; r < 4; ++r) {
                const float p = __expf(s[r]);   // scale pre-folded into Q
                rs[r] += p;                      // partial: cols j%16 == l16
                PbW[(quad * 4 + r) * 40 + jp * 16 + l16] = (bf16_t)p;
            }
        }
        __syncthreads();  // order P writes (cross-lane) before B-frag reads

        // O[c][i] += V[c][j] * P[i][j] : A=V frag, B=P^T frag (k=j, n=i)
        const bf16x8 pf = *(const bf16x8*)&PbW[l16 * 40 + quad * 8];
        for (int cp = 0; cp < 16; ++cp) {
            const bf16x8 vf = *(const bf16x8*)&Vt[(cp * 16 + l16) * 40 + quad * 8];
            oacc[cp] = __builtin_amdgcn_mfma_f32_16x16x32_bf16(vf, pf, oacc[cp], 0, 0, 0);
        }
        __syncthreads();  // before next tile's Kt/Vt staging
    }

    // reduce row sums across the 16 column-lanes (butterfly within quad)
    for (int r = 0; r < 4; ++r) {
        float v = rs[r];
        v += __shfl_xor(v, 1);
        v += __shfl_xor(v, 2);
        v += __shfl_xor(v, 4);
        v += __shfl_xor(v, 8);
        rs[r] = v;
    }
    if (l16 == 0)
        for (int r = 0; r < 4; ++r) lred[w * 16 + quad * 4 + r] = rs[r];
    __syncthreads();
    const float linv = 1.0f / lred[w * 16 + l16];  // l for i-local = l16

    // O lane element: c = cp*16 + quad*4 + r, i = i0 + w*16 + l16
    const int i = i0 + w * 16 + l16;
    for (int cp = 0; cp < 16; ++cp) {
        for (int r = 0; r < 4; ++r) {
            const int c = cp * 16 + quad * 4 + r;
            out[((size_t)b * CH + c) * NTOK + i] = oacc[cp][r] * linv;
        }
    }
}

// ---------------------------------------------------------------------------
extern "C" void kernel_launch(void* const* d_in, const int* in_sizes, int n_in,
                              void* d_out, int out_size, void* d_ws, size_t ws_size,
                              hipStream_t stream) {
    const float* x  = (const float*)d_in[0];
    const float* mi = (const float*)d_in[1];
    const float* wq = (const float*)d_in[2];
    const float* bq = (const float*)d_in[3];
    const float* wk = (const float*)d_in[4];
    const float* bk = (const float*)d_in[5];
    const float* wv = (const float*)d_in[6];
    const float* bv = (const float*)d_in[7];

    // workspace: Q,K,V bf16, 16 MB each (needs 48 MB of ws)
    bf16_t* qg = (bf16_t*)d_ws;
    bf16_t* kg = qg + (size_t)BATCH * NTOK * CH;
    bf16_t* vg = kg + (size_t)BATCH * NTOK * CH;

    dim3 pgrid(BATCH * (NTOK / 64), 3);
    proj_kernel<<<pgrid, 256, 0, stream>>>(x, mi, wq, bq, wk, bk, wv, bv, qg, kg, vg);
    attn_kernel<<<BATCH * (NTOK / 64), 256, 0, stream>>>(qg, kg, vg, (float*)d_out);
}